// Round 1
// baseline (1111.323 us; speedup 1.0000x reference)
//
#include <hip/hip_runtime.h>
#include <cstdint>
#include <cmath>

#define NB 256      // graphs (B)
#define MM 256      // nodes per graph
#define NN (NB*MM)  // 65536 nodes
#define KNN 15
#define FIN 7
#define CC 128
#define C2 768
#define NL 3

__device__ __forceinline__ float lrelu(float v){ return v > 0.f ? v : 0.01f*v; }

// ---------------------------------------------------------------- kNN -------
// One block per graph. Positions (4 floats) in LDS; each thread keeps a
// register-resident sorted top-15 (fully unrolled swap-chain insertion).
__global__ __launch_bounds__(256) void knn_kernel(const float* __restrict__ x,
                                                  int* __restrict__ knn){
  __shared__ float4 pos[MM];
  __shared__ float  sq[MM];
  const int g = blockIdx.x, t = threadIdx.x;
  const float* xr = x + (size_t)(g*MM + t)*FIN;
  float4 p = make_float4(xr[0], xr[1], xr[2], xr[3]);
  pos[t] = p;
  sq[t]  = p.x*p.x + p.y*p.y + p.z*p.z + p.w*p.w;
  __syncthreads();
  const float sqt = sq[t];
  float bd[KNN]; int bi[KNN];
#pragma unroll
  for (int i=0;i<KNN;i++){ bd[i]=3.4e38f; bi[i]=0; }
  for (int j=0;j<MM;j++){
    if (j == t) continue;                 // reference adds 1e10 on diagonal
    float4 q = pos[j];
    float dot = p.x*q.x + p.y*q.y + p.z*q.z + p.w*q.w;
    float d2 = sqt + sq[j] - 2.f*dot;     // same formula as reference
    if (d2 < bd[KNN-1]){
      float d = d2; int ix = j;
#pragma unroll
      for (int i=0;i<KNN;i++){
        if (d < bd[i]){ float td=bd[i]; int ti=bi[i]; bd[i]=d; bi[i]=ix; d=td; ix=ti; }
      }
    }
  }
  int* kn = knn + (size_t)(g*MM + t)*KNN;
#pragma unroll
  for (int i=0;i<KNN;i++) kn[i] = g*MM + bi[i];
}

// ------------------------------------------------------------ aggregation ---
// norm is constant 1/15 (every node is dst exactly 15 times -> deg==15).
__global__ void agg7_kernel(const float* __restrict__ src,
                            const int* __restrict__ knn,
                            float* __restrict__ out){
  int i = blockIdx.x*blockDim.x + threadIdx.x;
  if (i >= NN*FIN) return;
  int n = i / FIN, c = i - n*FIN;
  const int* kn = knn + (size_t)n*KNN;
  float s = 0.f;
#pragma unroll
  for (int k=0;k<KNN;k++) s += src[(size_t)kn[k]*FIN + c];
  out[i] = s * (1.f/15.f);
}

__global__ __launch_bounds__(128) void agg128_kernel(const float* __restrict__ src,
                                                     const int* __restrict__ knn,
                                                     float* __restrict__ out){
  const int n = blockIdx.x, c = threadIdx.x;
  const int* kn = knn + (size_t)n*KNN;
  float s = 0.f;
#pragma unroll
  for (int k=0;k<KNN;k++) s += src[(size_t)kn[k]*CC + c];
  out[(size_t)n*CC + c] = s * (1.f/15.f);
}

// ------------------------------------------------------------ conv layer 1 --
// K=7 per hop; stage the 21 input scalars in LDS, thread = output channel.
__global__ __launch_bounds__(128) void conv1_kernel(const float* __restrict__ x,
                                                    const float* __restrict__ a1,
                                                    const float* __restrict__ a2,
                                                    const float* __restrict__ W,
                                                    const float* __restrict__ b,
                                                    float* __restrict__ out){
  __shared__ float s[3*FIN];
  const int n = blockIdx.x, c = threadIdx.x;
  if (c < FIN)        s[c]      = x [(size_t)n*FIN + c];
  else if (c < 2*FIN) s[c]      = a1[(size_t)n*FIN + (c-FIN)];
  else if (c < 3*FIN) s[c]      = a2[(size_t)n*FIN + (c-2*FIN)];
  __syncthreads();
  float acc = b[c];
#pragma unroll
  for (int t=0;t<3*FIN;t++) acc += s[t] * W[t*CC + c];
  out[(size_t)n*CC + c] = lrelu(acc);
}

// -------------------------------------------------- conv layers 2/3 (GEMM) --
// out[N x 128] = lrelu( p0@W0 + p1@W1 + p2@W2 + b ), K=128 per hop.
// Tile 64 rows x 128 cols, 256 threads, 32 acc/thread. A staged transposed
// (k-major) so the inner loop uses ds_read_b128. Out may alias an input:
// each block reads only its own rows, writes them only at the very end.
#define CMT 64
__global__ __launch_bounds__(256) void conv_gemm_kernel(const float* __restrict__ p0,
                                                        const float* __restrict__ p1,
                                                        const float* __restrict__ p2,
                                                        const float* __restrict__ W,
                                                        const float* __restrict__ b,
                                                        float* __restrict__ out){
  __shared__ float Ast[32][CMT];   // [kk][r], stride 64 floats (16B aligned rows)
  __shared__ float Ws [32][CC];    // [kk][c]
  const int tid = threadIdx.x;
  const int row0 = blockIdx.x * CMT;
  const int tr = tid >> 5, tc = tid & 31;
  float acc[8][4];
#pragma unroll
  for (int i=0;i<8;i++)
#pragma unroll
    for (int j=0;j<4;j++) acc[i][j]=0.f;

#pragma unroll
  for (int hop=0; hop<3; hop++){
    const float* A  = (hop==0 ? p0 : hop==1 ? p1 : p2) + (size_t)row0*CC;
    const float* Wh = W + (size_t)hop*CC*CC;
    for (int kt=0; kt<4; kt++){
      __syncthreads();
      // stage A: 64 rows x 32 k, transposed
#pragma unroll
      for (int q=0;q<2;q++){
        int chunk = tid + q*256;
        int r   = chunk >> 3;
        int kc4 = (chunk & 7) * 4;
        float4 v = *(const float4*)(A + (size_t)r*CC + kt*32 + kc4);
        Ast[kc4+0][r] = v.x; Ast[kc4+1][r] = v.y;
        Ast[kc4+2][r] = v.z; Ast[kc4+3][r] = v.w;
      }
      // stage W: 32 k x 128 c
#pragma unroll
      for (int q=0;q<4;q++){
        int chunk = tid + q*256;
        int kr = chunk >> 5;
        int c4 = (chunk & 31) * 4;
        *(float4*)(&Ws[kr][c4]) = *(const float4*)(Wh + (size_t)(kt*32+kr)*CC + c4);
      }
      __syncthreads();
#pragma unroll 8
      for (int kk=0;kk<32;kk++){
        float4 w  = *(const float4*)(&Ws[kk][tc*4]);
        float4 a0 = *(const float4*)(&Ast[kk][tr*8]);
        float4 a1 = *(const float4*)(&Ast[kk][tr*8+4]);
        float av[8] = {a0.x,a0.y,a0.z,a0.w,a1.x,a1.y,a1.z,a1.w};
        float wv[4] = {w.x,w.y,w.z,w.w};
#pragma unroll
        for (int i=0;i<8;i++)
#pragma unroll
          for (int j=0;j<4;j++) acc[i][j] += av[i]*wv[j];
      }
    }
  }
  const int c0 = tc*4;
  float4 bv = *(const float4*)(b + c0);
  float bb[4] = {bv.x,bv.y,bv.z,bv.w};
#pragma unroll
  for (int i=0;i<8;i++){
    int r = row0 + tr*8 + i;
    float4 o;
    o.x = lrelu(acc[i][0]+bb[0]);
    o.y = lrelu(acc[i][1]+bb[1]);
    o.z = lrelu(acc[i][2]+bb[2]);
    o.w = lrelu(acc[i][3]+bb[3]);
    *(float4*)(out + (size_t)r*CC + c0) = o;
  }
}

// ------------------------------------------------------------------ pooling -
__global__ __launch_bounds__(128) void pool_kernel(const float* __restrict__ h,
                                                   float* __restrict__ gf, int off){
  const int g = blockIdx.x, c = threadIdx.x;
  const float* hp = h + (size_t)g*MM*CC + c;
  float s = 0.f, mx = -3.4e38f;
  for (int m=0;m<MM;m++){
    float v = hp[(size_t)m*CC];
    s += v; mx = fmaxf(mx, v);
  }
  gf[(size_t)g*C2 + off + c]      = s * (1.f/MM);
  gf[(size_t)g*C2 + off + CC + c] = mx;
}

// ---------------------------------------------------------------- batchnorm -
__global__ __launch_bounds__(256) void bn_kernel(float* __restrict__ g,
                                                 const float* __restrict__ gamma,
                                                 const float* __restrict__ beta){
  const int c = blockIdx.x*256 + threadIdx.x;   // 0..767
  float s=0.f, sq=0.f;
  for (int r=0;r<NB;r++){
    float v = g[(size_t)r*C2 + c];
    s += v; sq += v*v;
  }
  float mu  = s * (1.f/NB);
  float var = sq * (1.f/NB) - mu*mu;
  float scale = rsqrtf(var + 1e-5f) * gamma[c];
  float shift = beta[c] - mu*scale;
  for (int r=0;r<NB;r++){
    size_t ix = (size_t)r*C2 + c;
    g[ix] = g[ix]*scale + shift;
  }
}

// -------------------------------------------------------------- MLP (GEMM) --
// out[256 x 768] = lrelu(A @ W + b). Tile 16 rows x 128 cols, grid (6,16).
__global__ __launch_bounds__(256) void mlp_gemm_kernel(const float* __restrict__ A,
                                                       const float* __restrict__ W,
                                                       const float* __restrict__ b,
                                                       float* __restrict__ out){
  __shared__ float Ast[32][16];
  __shared__ float Ws [32][128];
  const int tid = threadIdx.x;
  const int row0 = blockIdx.y * 16;
  const int col0 = blockIdx.x * 128;
  const int tr = tid >> 5, tc = tid & 31;
  float acc[2][4] = {{0.f,0.f,0.f,0.f},{0.f,0.f,0.f,0.f}};
  for (int kt=0; kt<24; kt++){
    __syncthreads();
    if (tid < 128){
      int r   = tid >> 3;
      int kc4 = (tid & 7)*4;
      float4 v = *(const float4*)(A + (size_t)(row0+r)*C2 + kt*32 + kc4);
      Ast[kc4+0][r]=v.x; Ast[kc4+1][r]=v.y; Ast[kc4+2][r]=v.z; Ast[kc4+3][r]=v.w;
    }
#pragma unroll
    for (int q=0;q<4;q++){
      int chunk = tid + q*256;
      int kr = chunk >> 5;
      int c4 = (chunk & 31)*4;
      *(float4*)(&Ws[kr][c4]) = *(const float4*)(W + (size_t)(kt*32+kr)*C2 + col0 + c4);
    }
    __syncthreads();
#pragma unroll 8
    for (int kk=0;kk<32;kk++){
      float4 w = *(const float4*)(&Ws[kk][tc*4]);
      float a0 = Ast[kk][tr*2+0];
      float a1 = Ast[kk][tr*2+1];
      acc[0][0] += a0*w.x; acc[0][1] += a0*w.y; acc[0][2] += a0*w.z; acc[0][3] += a0*w.w;
      acc[1][0] += a1*w.x; acc[1][1] += a1*w.y; acc[1][2] += a1*w.z; acc[1][3] += a1*w.w;
    }
  }
  const int c0 = col0 + tc*4;
  float4 bv = *(const float4*)(b + c0);
#pragma unroll
  for (int i=0;i<2;i++){
    int r = row0 + tr*2 + i;
    float4 o;
    o.x = lrelu(acc[i][0]+bv.x);
    o.y = lrelu(acc[i][1]+bv.y);
    o.z = lrelu(acc[i][2]+bv.z);
    o.w = lrelu(acc[i][3]+bv.w);
    *(float4*)(out + (size_t)r*C2 + c0) = o;
  }
}

// ------------------------------------------------------------- final layer --
__global__ __launch_bounds__(256) void final_kernel(const float* __restrict__ g,
                                                    const float* __restrict__ Wo,
                                                    const float* __restrict__ bo,
                                                    float* __restrict__ out){
  int i = blockIdx.x*256 + threadIdx.x;   // 0..767
  if (i >= NB*NL) return;
  int r = i / NL, c = i - r*NL;
  const float* gr = g + (size_t)r*C2;
  float acc = bo[c];
  for (int k=0;k<C2;k++) acc += gr[k]*Wo[k*NL + c];
  if (c < 2) acc = tanhf(acc);
  out[i] = acc;
}

// ------------------------------------------------------------------ launch --
extern "C" void kernel_launch(void* const* d_in, const int* in_sizes, int n_in,
                              void* d_out, int out_size, void* d_ws, size_t ws_size,
                              hipStream_t stream){
  const float* x   = (const float*)d_in[0];
  const float* Wc1 = (const float*)d_in[1];
  const float* bc1 = (const float*)d_in[2];
  const float* Wc2 = (const float*)d_in[3];
  const float* bc2 = (const float*)d_in[4];
  const float* Wc3 = (const float*)d_in[5];
  const float* bc3 = (const float*)d_in[6];
  const float* bng = (const float*)d_in[7];
  const float* bnb = (const float*)d_in[8];
  const float* W1  = (const float*)d_in[9];
  const float* b1  = (const float*)d_in[10];
  const float* W2  = (const float*)d_in[11];
  const float* b2  = (const float*)d_in[12];
  const float* W3  = (const float*)d_in[13];
  const float* b3  = (const float*)d_in[14];
  const float* W4  = (const float*)d_in[15];
  const float* b4  = (const float*)d_in[16];
  const float* W5  = (const float*)d_in[17];
  const float* b5  = (const float*)d_in[18];
  const float* Wo  = (const float*)d_in[19];
  const float* bo  = (const float*)d_in[20];

  char* ws = (char*)d_ws;
  size_t o = 0;
  int*   knn = (int*)  (ws + o); o += (size_t)NN*KNN*4;   // 3.93 MB
  float* h0  = (float*)(ws + o); o += (size_t)NN*CC*4;    // 33.5 MB
  float* h1  = (float*)(ws + o); o += (size_t)NN*CC*4;    // 33.5 MB
  float* h2  = (float*)(ws + o); o += (size_t)NN*CC*4;    // 33.5 MB
  float* gf  = (float*)(ws + o); o += (size_t)NB*C2*4;    // 0.79 MB
  float* gt  = (float*)(ws + o); o += (size_t)NB*C2*4;    // 0.79 MB
  // layer-1 (7-channel) aggregates live in the not-yet-used h1/h2 regions
  float* ax1 = h1;
  float* ax2 = h2;

  knn_kernel<<<NB, MM, 0, stream>>>(x, knn);

  const int tot7 = NN*FIN;
  agg7_kernel<<<(tot7+255)/256, 256, 0, stream>>>(x,   knn, ax1);
  agg7_kernel<<<(tot7+255)/256, 256, 0, stream>>>(ax1, knn, ax2);
  conv1_kernel<<<NN, CC, 0, stream>>>(x, ax1, ax2, Wc1, bc1, h0);
  pool_kernel<<<NB, CC, 0, stream>>>(h0, gf, 0);

  agg128_kernel<<<NN, CC, 0, stream>>>(h0, knn, h1);
  agg128_kernel<<<NN, CC, 0, stream>>>(h1, knn, h2);
  conv_gemm_kernel<<<NN/CMT, 256, 0, stream>>>(h0, h1, h2, Wc2, bc2, h1);
  pool_kernel<<<NB, CC, 0, stream>>>(h1, gf, 2*CC);

  agg128_kernel<<<NN, CC, 0, stream>>>(h1, knn, h0);
  agg128_kernel<<<NN, CC, 0, stream>>>(h0, knn, h2);
  conv_gemm_kernel<<<NN/CMT, 256, 0, stream>>>(h1, h0, h2, Wc3, bc3, h0);
  pool_kernel<<<NB, CC, 0, stream>>>(h0, gf, 4*CC);

  bn_kernel<<<3, 256, 0, stream>>>(gf, bng, bnb);

  dim3 mgrid(6, 16);
  mlp_gemm_kernel<<<mgrid, 256, 0, stream>>>(gf, W1, b1, gt);
  mlp_gemm_kernel<<<mgrid, 256, 0, stream>>>(gt, W2, b2, gf);
  mlp_gemm_kernel<<<mgrid, 256, 0, stream>>>(gf, W3, b3, gt);
  mlp_gemm_kernel<<<mgrid, 256, 0, stream>>>(gt, W4, b4, gf);
  mlp_gemm_kernel<<<mgrid, 256, 0, stream>>>(gf, W5, b5, gt);

  final_kernel<<<3, 256, 0, stream>>>(gt, Wo, bo, (float*)d_out);
}

// Round 2
// 913.678 us; speedup vs baseline: 1.2163x; 1.2163x over previous
//
#include <hip/hip_runtime.h>
#include <cstdint>
#include <cmath>

#define NB 256      // graphs (B)
#define MM 256      // nodes per graph
#define NN (NB*MM)  // 65536 nodes
#define KNN 15
#define FIN 7
#define CC 128
#define C2 768
#define NL 3
#define FINF 3.4e38f

__device__ __forceinline__ float lrelu(float v){ return v > 0.f ? v : 0.01f*v; }

// ---------------------------------------------------------------- kNN -------
// Wave-per-node: 4 waves/block, 64 blocks/graph -> 16384 blocks (32 waves/CU
// achievable vs 4 in R1). Lane l owns candidates j = {l, 64+l, 128+l, 192+l}.
// 15 rounds of wave-wide argmin via shfl_xor butterfly over the total order
// (d, idx) -> deterministic, matches stable top_k (order within the 15 is
// irrelevant downstream: only the neighbor SET feeds segment_sum).
__global__ __launch_bounds__(256) void knn_kernel(const float* __restrict__ x,
                                                  int* __restrict__ knn){
  __shared__ float4 pos[MM];
  __shared__ float  sq[MM];
  const int g = blockIdx.x >> 6;               // 64 blocks per graph
  const int t = threadIdx.x;
  const float* xr = x + (size_t)(g*MM + t)*FIN;
  float4 p = make_float4(xr[0], xr[1], xr[2], xr[3]);
  pos[t] = p;
  sq[t]  = p.x*p.x + p.y*p.y + p.z*p.z + p.w*p.w;
  __syncthreads();

  const int i    = (blockIdx.x & 63)*4 + (t >> 6);  // local node this wave owns
  const int lane = t & 63;
  const float4 pi = pos[i];
  const float  sqi = sq[i];

  float d[4];
#pragma unroll
  for (int q=0;q<4;q++){
    int j = q*64 + lane;
    float4 pj = pos[j];
    float dot = pi.x*pj.x + pi.y*pj.y + pi.z*pj.z + pi.w*pj.w;
    d[q] = sqi + sq[j] - 2.f*dot;
    if (j == i) d[q] = FINF;                  // self-exclusion
  }

  int keep = 0;
#pragma unroll
  for (int it=0; it<KNN; it++){
    // local argmin of 4 (static indices only -> stays in VGPRs)
    float lm = d[0]; int lq = 0;
    if (d[1] < lm){ lm = d[1]; lq = 1; }
    if (d[2] < lm){ lm = d[2]; lq = 2; }
    if (d[3] < lm){ lm = d[3]; lq = 3; }
    float bd = lm; int bi = lq*64 + lane;
    // 64-lane butterfly argmin; (d, idx) is a total order -> all lanes agree
#pragma unroll
    for (int off=1; off<64; off<<=1){
      float od = __shfl_xor(bd, off);
      int   oi = __shfl_xor(bi, off);
      if (od < bd || (od == bd && oi < bi)){ bd = od; bi = oi; }
    }
    if (lane == it) keep = bi;
    // consume the winner (static-indexed cndmasks)
#pragma unroll
    for (int q=0;q<4;q++) if (bi == q*64 + lane) d[q] = FINF;
  }
  if (lane < KNN)
    knn[(size_t)(g*MM + i)*KNN + lane] = g*MM + keep;
}

// ------------------------------------------------------------ aggregation ---
// norm is constant 1/15 (every node is dst exactly 15 times -> deg==15).
__global__ void agg7_kernel(const float* __restrict__ src,
                            const int* __restrict__ knn,
                            float* __restrict__ out){
  int i = blockIdx.x*blockDim.x + threadIdx.x;
  if (i >= NN*FIN) return;
  int n = i / FIN, c = i - n*FIN;
  const int* kn = knn + (size_t)n*KNN;
  float s = 0.f;
#pragma unroll
  for (int k=0;k<KNN;k++) s += src[(size_t)kn[k]*FIN + c];
  out[i] = s * (1.f/15.f);
}

// 4 nodes per 128-thread block, float4 per thread: 1/4 the VMEM instructions
// of the R1 version; gathers are 512B contiguous per 32-lane group (L2-hot).
__global__ __launch_bounds__(128) void agg128_kernel(const float* __restrict__ src,
                                                     const int* __restrict__ knn,
                                                     float* __restrict__ out){
  const int tid = threadIdx.x;
  const int n   = blockIdx.x*4 + (tid >> 5);
  const int c4  = (tid & 31) * 4;
  const int* kn = knn + (size_t)n*KNN;
  float4 s = make_float4(0.f,0.f,0.f,0.f);
#pragma unroll
  for (int k=0;k<KNN;k++){
    float4 v = *(const float4*)(src + (size_t)kn[k]*CC + c4);
    s.x += v.x; s.y += v.y; s.z += v.z; s.w += v.w;
  }
  float4 o = make_float4(s.x*(1.f/15.f), s.y*(1.f/15.f),
                         s.z*(1.f/15.f), s.w*(1.f/15.f));
  *(float4*)(out + (size_t)n*CC + c4) = o;
}

// ------------------------------------------------------------ conv layer 1 --
__global__ __launch_bounds__(128) void conv1_kernel(const float* __restrict__ x,
                                                    const float* __restrict__ a1,
                                                    const float* __restrict__ a2,
                                                    const float* __restrict__ W,
                                                    const float* __restrict__ b,
                                                    float* __restrict__ out){
  __shared__ float s[3*FIN];
  const int n = blockIdx.x, c = threadIdx.x;
  if (c < FIN)        s[c] = x [(size_t)n*FIN + c];
  else if (c < 2*FIN) s[c] = a1[(size_t)n*FIN + (c-FIN)];
  else if (c < 3*FIN) s[c] = a2[(size_t)n*FIN + (c-2*FIN)];
  __syncthreads();
  float acc = b[c];
#pragma unroll
  for (int t=0;t<3*FIN;t++) acc += s[t] * W[t*CC + c];
  out[(size_t)n*CC + c] = lrelu(acc);
}

// -------------------------------------------------- conv layers 2/3 (GEMM) --
#define CMT 64
__global__ __launch_bounds__(256) void conv_gemm_kernel(const float* __restrict__ p0,
                                                        const float* __restrict__ p1,
                                                        const float* __restrict__ p2,
                                                        const float* __restrict__ W,
                                                        const float* __restrict__ b,
                                                        float* __restrict__ out){
  __shared__ float Ast[32][CMT];   // [kk][r]
  __shared__ float Ws [32][CC];    // [kk][c]
  const int tid = threadIdx.x;
  const int row0 = blockIdx.x * CMT;
  const int tr = tid >> 5, tc = tid & 31;
  float acc[8][4];
#pragma unroll
  for (int i=0;i<8;i++)
#pragma unroll
    for (int j=0;j<4;j++) acc[i][j]=0.f;

#pragma unroll
  for (int hop=0; hop<3; hop++){
    const float* A  = (hop==0 ? p0 : hop==1 ? p1 : p2) + (size_t)row0*CC;
    const float* Wh = W + (size_t)hop*CC*CC;
    for (int kt=0; kt<4; kt++){
      __syncthreads();
#pragma unroll
      for (int q=0;q<2;q++){
        int chunk = tid + q*256;
        int r   = chunk >> 3;
        int kc4 = (chunk & 7) * 4;
        float4 v = *(const float4*)(A + (size_t)r*CC + kt*32 + kc4);
        Ast[kc4+0][r] = v.x; Ast[kc4+1][r] = v.y;
        Ast[kc4+2][r] = v.z; Ast[kc4+3][r] = v.w;
      }
#pragma unroll
      for (int q=0;q<4;q++){
        int chunk = tid + q*256;
        int kr = chunk >> 5;
        int c4 = (chunk & 31) * 4;
        *(float4*)(&Ws[kr][c4]) = *(const float4*)(Wh + (size_t)(kt*32+kr)*CC + c4);
      }
      __syncthreads();
#pragma unroll 8
      for (int kk=0;kk<32;kk++){
        float4 w  = *(const float4*)(&Ws[kk][tc*4]);
        float4 a0 = *(const float4*)(&Ast[kk][tr*8]);
        float4 a1 = *(const float4*)(&Ast[kk][tr*8+4]);
        float av[8] = {a0.x,a0.y,a0.z,a0.w,a1.x,a1.y,a1.z,a1.w};
        float wv[4] = {w.x,w.y,w.z,w.w};
#pragma unroll
        for (int i=0;i<8;i++)
#pragma unroll
          for (int j=0;j<4;j++) acc[i][j] += av[i]*wv[j];
      }
    }
  }
  const int c0 = tc*4;
  float4 bv = *(const float4*)(b + c0);
  float bb[4] = {bv.x,bv.y,bv.z,bv.w};
#pragma unroll
  for (int i=0;i<8;i++){
    int r = row0 + tr*8 + i;
    float4 o;
    o.x = lrelu(acc[i][0]+bb[0]);
    o.y = lrelu(acc[i][1]+bb[1]);
    o.z = lrelu(acc[i][2]+bb[2]);
    o.w = lrelu(acc[i][3]+bb[3]);
    *(float4*)(out + (size_t)r*CC + c0) = o;
  }
}

// ------------------------------------------------------------------ pooling -
// 4 row-groups x 128 channels; LDS combine. 4x the parallelism of R1 version.
__global__ __launch_bounds__(512) void pool_kernel(const float* __restrict__ h,
                                                   float* __restrict__ gf, int off){
  __shared__ float smean[4][CC];
  __shared__ float smax [4][CC];
  const int g = blockIdx.x, tid = threadIdx.x;
  const int c = tid & 127, grp = tid >> 7;
  const float* hp = h + (size_t)g*MM*CC + c;
  float s = 0.f, mx = -FINF;
  for (int m=grp*64; m<grp*64+64; m++){
    float v = hp[(size_t)m*CC];
    s += v; mx = fmaxf(mx, v);
  }
  smean[grp][c] = s; smax[grp][c] = mx;
  __syncthreads();
  if (grp == 0){
    s  = smean[0][c] + smean[1][c] + smean[2][c] + smean[3][c];
    mx = fmaxf(fmaxf(smax[0][c], smax[1][c]), fmaxf(smax[2][c], smax[3][c]));
    gf[(size_t)g*C2 + off + c]      = s * (1.f/MM);
    gf[(size_t)g*C2 + off + CC + c] = mx;
  }
}

// ---------------------------------------------------------------- batchnorm -
__global__ __launch_bounds__(256) void bn_kernel(float* __restrict__ g,
                                                 const float* __restrict__ gamma,
                                                 const float* __restrict__ beta){
  const int c = blockIdx.x*256 + threadIdx.x;   // 0..767
  float s=0.f, sq=0.f;
  for (int r=0;r<NB;r++){
    float v = g[(size_t)r*C2 + c];
    s += v; sq += v*v;
  }
  float mu  = s * (1.f/NB);
  float var = sq * (1.f/NB) - mu*mu;
  float scale = rsqrtf(var + 1e-5f) * gamma[c];
  float shift = beta[c] - mu*scale;
  for (int r=0;r<NB;r++){
    size_t ix = (size_t)r*C2 + c;
    g[ix] = g[ix]*scale + shift;
  }
}

// -------------------------------------------------------------- MLP (GEMM) --
__global__ __launch_bounds__(256) void mlp_gemm_kernel(const float* __restrict__ A,
                                                       const float* __restrict__ W,
                                                       const float* __restrict__ b,
                                                       float* __restrict__ out){
  __shared__ float Ast[32][16];
  __shared__ float Ws [32][128];
  const int tid = threadIdx.x;
  const int row0 = blockIdx.y * 16;
  const int col0 = blockIdx.x * 128;
  const int tr = tid >> 5, tc = tid & 31;
  float acc[2][4] = {{0.f,0.f,0.f,0.f},{0.f,0.f,0.f,0.f}};
  for (int kt=0; kt<24; kt++){
    __syncthreads();
    if (tid < 128){
      int r   = tid >> 3;
      int kc4 = (tid & 7)*4;
      float4 v = *(const float4*)(A + (size_t)(row0+r)*C2 + kt*32 + kc4);
      Ast[kc4+0][r]=v.x; Ast[kc4+1][r]=v.y; Ast[kc4+2][r]=v.z; Ast[kc4+3][r]=v.w;
    }
#pragma unroll
    for (int q=0;q<4;q++){
      int chunk = tid + q*256;
      int kr = chunk >> 5;
      int c4 = (chunk & 31)*4;
      *(float4*)(&Ws[kr][c4]) = *(const float4*)(W + (size_t)(kt*32+kr)*C2 + col0 + c4);
    }
    __syncthreads();
#pragma unroll 8
    for (int kk=0;kk<32;kk++){
      float4 w = *(const float4*)(&Ws[kk][tc*4]);
      float a0 = Ast[kk][tr*2+0];
      float a1 = Ast[kk][tr*2+1];
      acc[0][0] += a0*w.x; acc[0][1] += a0*w.y; acc[0][2] += a0*w.z; acc[0][3] += a0*w.w;
      acc[1][0] += a1*w.x; acc[1][1] += a1*w.y; acc[1][2] += a1*w.z; acc[1][3] += a1*w.w;
    }
  }
  const int c0 = col0 + tc*4;
  float4 bv = *(const float4*)(b + c0);
#pragma unroll
  for (int i=0;i<2;i++){
    int r = row0 + tr*2 + i;
    float4 o;
    o.x = lrelu(acc[i][0]+bv.x);
    o.y = lrelu(acc[i][1]+bv.y);
    o.z = lrelu(acc[i][2]+bv.z);
    o.w = lrelu(acc[i][3]+bv.w);
    *(float4*)(out + (size_t)r*C2 + c0) = o;
  }
}

// ------------------------------------------------------------- final layer --
__global__ __launch_bounds__(256) void final_kernel(const float* __restrict__ g,
                                                    const float* __restrict__ Wo,
                                                    const float* __restrict__ bo,
                                                    float* __restrict__ out){
  int i = blockIdx.x*256 + threadIdx.x;   // 0..767
  if (i >= NB*NL) return;
  int r = i / NL, c = i - r*NL;
  const float* gr = g + (size_t)r*C2;
  float acc = bo[c];
  for (int k=0;k<C2;k++) acc += gr[k]*Wo[k*NL + c];
  if (c < 2) acc = tanhf(acc);
  out[i] = acc;
}

// ------------------------------------------------------------------ launch --
extern "C" void kernel_launch(void* const* d_in, const int* in_sizes, int n_in,
                              void* d_out, int out_size, void* d_ws, size_t ws_size,
                              hipStream_t stream){
  const float* x   = (const float*)d_in[0];
  const float* Wc1 = (const float*)d_in[1];
  const float* bc1 = (const float*)d_in[2];
  const float* Wc2 = (const float*)d_in[3];
  const float* bc2 = (const float*)d_in[4];
  const float* Wc3 = (const float*)d_in[5];
  const float* bc3 = (const float*)d_in[6];
  const float* bng = (const float*)d_in[7];
  const float* bnb = (const float*)d_in[8];
  const float* W1  = (const float*)d_in[9];
  const float* b1  = (const float*)d_in[10];
  const float* W2  = (const float*)d_in[11];
  const float* b2  = (const float*)d_in[12];
  const float* W3  = (const float*)d_in[13];
  const float* b3  = (const float*)d_in[14];
  const float* W4  = (const float*)d_in[15];
  const float* b4  = (const float*)d_in[16];
  const float* W5  = (const float*)d_in[17];
  const float* b5  = (const float*)d_in[18];
  const float* Wo  = (const float*)d_in[19];
  const float* bo  = (const float*)d_in[20];

  char* ws = (char*)d_ws;
  size_t o = 0;
  int*   knn = (int*)  (ws + o); o += (size_t)NN*KNN*4;
  float* h0  = (float*)(ws + o); o += (size_t)NN*CC*4;
  float* h1  = (float*)(ws + o); o += (size_t)NN*CC*4;
  float* h2  = (float*)(ws + o); o += (size_t)NN*CC*4;
  float* gf  = (float*)(ws + o); o += (size_t)NB*C2*4;
  float* gt  = (float*)(ws + o); o += (size_t)NB*C2*4;
  float* ax1 = h1;
  float* ax2 = h2;

  knn_kernel<<<NB*64, 256, 0, stream>>>(x, knn);

  const int tot7 = NN*FIN;
  agg7_kernel<<<(tot7+255)/256, 256, 0, stream>>>(x,   knn, ax1);
  agg7_kernel<<<(tot7+255)/256, 256, 0, stream>>>(ax1, knn, ax2);
  conv1_kernel<<<NN, CC, 0, stream>>>(x, ax1, ax2, Wc1, bc1, h0);
  pool_kernel<<<NB, 512, 0, stream>>>(h0, gf, 0);

  agg128_kernel<<<NN/4, 128, 0, stream>>>(h0, knn, h1);
  agg128_kernel<<<NN/4, 128, 0, stream>>>(h1, knn, h2);
  conv_gemm_kernel<<<NN/CMT, 256, 0, stream>>>(h0, h1, h2, Wc2, bc2, h1);
  pool_kernel<<<NB, 512, 0, stream>>>(h1, gf, 2*CC);

  agg128_kernel<<<NN/4, 128, 0, stream>>>(h1, knn, h0);
  agg128_kernel<<<NN/4, 128, 0, stream>>>(h0, knn, h2);
  conv_gemm_kernel<<<NN/CMT, 256, 0, stream>>>(h1, h0, h2, Wc3, bc3, h0);
  pool_kernel<<<NB, 512, 0, stream>>>(h0, gf, 4*CC);

  bn_kernel<<<3, 256, 0, stream>>>(gf, bng, bnb);

  dim3 mgrid(6, 16);
  mlp_gemm_kernel<<<mgrid, 256, 0, stream>>>(gf, W1, b1, gt);
  mlp_gemm_kernel<<<mgrid, 256, 0, stream>>>(gt, W2, b2, gf);
  mlp_gemm_kernel<<<mgrid, 256, 0, stream>>>(gf, W3, b3, gt);
  mlp_gemm_kernel<<<mgrid, 256, 0, stream>>>(gt, W4, b4, gf);
  mlp_gemm_kernel<<<mgrid, 256, 0, stream>>>(gf, W5, b5, gt);

  final_kernel<<<3, 256, 0, stream>>>(gt, Wo, bo, (float*)d_out);
}